// Round 13
// baseline (358.884 us; speedup 1.0000x reference)
//
#include <hip/hip_runtime.h>
#include <hip/hip_cooperative_groups.h>

namespace cg = cooperative_groups;

#define BB 64
#define CC 128
#define HH 80
#define WW 80
#define HW 6400
#define SIG2F 0.18f   // 2 * 0.3^2

typedef float f4v __attribute__((ext_vector_type(4)));

__device__ __forceinline__ float dot4(f4v a, f4v b) {
    return a.x * b.x + a.y * b.y + a.z * b.z + a.w * b.w;
}

// half-block (128-thread) sum; node 0 = t<128, node 1 = t>=128 reduce
// independently; result broadcast within each half. All 256 threads call.
__device__ __forceinline__ float halfsum256(float v, int t, float* red4) {
    for (int off = 32; off > 0; off >>= 1) v += __shfl_down(v, off, 64);
    __syncthreads();
    if ((t & 63) == 0) red4[t >> 6] = v;
    __syncthreads();
    int base = (t >> 7) * 2;
    return red4[base] + red4[base + 1];
}

// ---------------------------------------------------------------------------
// attention + FFN + LN core, shared by cooperative phase B and fallback attn.
// 256 threads; nodes_raw are unnormalized pool sums; writes h2 (and spos4 out).
// ---------------------------------------------------------------------------
__device__ __forceinline__ void attn_core(
        int b, int tid,
        const float* __restrict__ nodes, const float* __restrict__ mstat,
        const float* __restrict__ wq, const float* __restrict__ bq,
        const float* __restrict__ wk, const float* __restrict__ bk,
        const float* __restrict__ wv, const float* __restrict__ bv,
        const float* __restrict__ wo, const float* __restrict__ bo,
        const float* __restrict__ g1, const float* __restrict__ be1,
        const float* __restrict__ g2, const float* __restrict__ be2,
        const float* __restrict__ w1, const float* __restrict__ bf1,
        const float* __restrict__ w2, const float* __restrict__ bf2,
        float* __restrict__ h2g, float* __restrict__ pos_out) {
    int n = tid >> 7, ch = tid & 127;
    __shared__ __align__(16) float sn[2][128], sq[2][128], sk[2][128], sv[2][128];
    __shared__ __align__(16) float sao[2][128], shh[2][128], sf[2][256];
    __shared__ float attnw[4][2][2];
    __shared__ float ared4[4];
    __shared__ float spos[4];
    __shared__ float sinv2[2];
    if (tid < 2) {
        const f4v* q = (const f4v*)(mstat + ((size_t)(b * 2 + tid) * 4) * 4);
        f4v acc = q[0] + q[1] + q[2] + q[3];   // {F, C, SY, SX}
        spos[tid * 2 + 0] = (acc.w / acc.y) * (2.f / (float)WW) - 1.f;
        spos[tid * 2 + 1] = (acc.z / acc.y) * (2.f / (float)HH) - 1.f;
        sinv2[tid] = 1.f / (acc.x + 1e-6f);
    }
    __syncthreads();
    float nv = nodes[(size_t)(b * 2 + n) * 128 + ch] * sinv2[n];
    sn[n][ch] = nv;
    __syncthreads();
    {
        float q = bq[ch], k = bk[ch], v = bv[ch];
        const f4v* wq4 = (const f4v*)(wq + (size_t)ch * 128);
        const f4v* wk4 = (const f4v*)(wk + (size_t)ch * 128);
        const f4v* wv4 = (const f4v*)(wv + (size_t)ch * 128);
        const f4v* snn = (const f4v*)sn[n];
        #pragma unroll 4
        for (int c4 = 0; c4 < 32; c4++) {
            f4v a = snn[c4];
            q += dot4(wq4[c4], a);
            k += dot4(wk4[c4], a);
            v += dot4(wv4[c4], a);
        }
        sq[n][ch] = q; sk[n][ch] = k; sv[n][ch] = v;
    }
    __syncthreads();
    if (tid < 128) {
        float q0 = sq[0][tid], q1 = sq[1][tid], k0 = sk[0][tid], k1 = sk[1][tid];
        float s00 = q0 * k0, s01 = q0 * k1, s10 = q1 * k0, s11 = q1 * k1;
        for (int off = 16; off > 0; off >>= 1) {
            s00 += __shfl_down(s00, off, 32);
            s01 += __shfl_down(s01, off, 32);
            s10 += __shfl_down(s10, off, 32);
            s11 += __shfl_down(s11, off, 32);
        }
        if ((tid & 31) == 0) {
            int h = tid >> 5;
            const float sc = 0.17677669529663687f;     // 1/sqrt(32)
            float dxp = spos[0] - spos[2];
            float dyp = spos[1] - spos[3];
            float D = sqrtf(dxp * dxp + dyp * dyp);
            float l0 = s00 * sc, l1 = s01 * sc - D;
            float mx = fmaxf(l0, l1);
            float e0 = __expf(l0 - mx), e1 = __expf(l1 - mx);
            float inv = 1.f / (e0 + e1);
            attnw[h][0][0] = e0 * inv; attnw[h][0][1] = e1 * inv;
            l0 = s10 * sc - D; l1 = s11 * sc;
            mx = fmaxf(l0, l1);
            e0 = __expf(l0 - mx); e1 = __expf(l1 - mx);
            inv = 1.f / (e0 + e1);
            attnw[h][1][0] = e0 * inv; attnw[h][1][1] = e1 * inv;
        }
    }
    __syncthreads();
    {
        int hh = ch >> 5;
        sao[n][ch] = attnw[hh][n][0] * sv[0][ch] + attnw[hh][n][1] * sv[1][ch];
    }
    __syncthreads();
    float r;
    {
        float o = bo[ch];
        const f4v* wo4 = (const f4v*)(wo + (size_t)ch * 128);
        const f4v* saon = (const f4v*)sao[n];
        #pragma unroll 4
        for (int c4 = 0; c4 < 32; c4++) o += dot4(wo4[c4], saon[c4]);
        r = nv + o;
    }
    float mu = halfsum256(r, tid, ared4) * (1.f / 128.f);
    float d = r - mu;
    float var = halfsum256(d * d, tid, ared4) * (1.f / 128.f);
    float h = d * rsqrtf(var + 1e-5f) * g1[ch] + be1[ch];
    shh[n][ch] = h;
    __syncthreads();
    {
        float a0 = bf1[tid], a1 = bf1[tid];
        const f4v* w14 = (const f4v*)(w1 + (size_t)tid * 128);
        const f4v* sh0 = (const f4v*)shh[0];
        const f4v* sh1 = (const f4v*)shh[1];
        #pragma unroll 4
        for (int c4 = 0; c4 < 32; c4++) {
            f4v w = w14[c4];
            a0 += dot4(w, sh0[c4]);
            a1 += dot4(w, sh1[c4]);
        }
        sf[0][tid] = fmaxf(a0, 0.f);
        sf[1][tid] = fmaxf(a1, 0.f);
    }
    __syncthreads();
    float r2;
    {
        float a = bf2[ch];
        const f4v* w24 = (const f4v*)(w2 + (size_t)ch * 256);
        const f4v* sfn = (const f4v*)sf[n];
        #pragma unroll 4
        for (int j4 = 0; j4 < 64; j4++) a += dot4(w24[j4], sfn[j4]);
        r2 = h + a;
    }
    float m2 = halfsum256(r2, tid, ared4) * (1.f / 128.f);
    float e = r2 - m2;
    float v2 = halfsum256(e * e, tid, ared4) * (1.f / 128.f);
    h2g[(size_t)(b * 2 + n) * 128 + ch] = e * rsqrtf(v2 + 1e-5f) * g2[ch] + be2[ch];
    if (pos_out && tid < 4) pos_out[b * 4 + tid] = spos[tid];
}

// ---------------------------------------------------------------------------
// Kernel A: nearest-resize masks (640->80 = stride-8 sample), row-chunked.
// grid: 128 planes x 4 chunks = 512 blocks, 256 threads.
// ---------------------------------------------------------------------------
__global__ __launch_bounds__(256) void mask_kernel(const float* __restrict__ masks,
                                                   float* __restrict__ m_res,
                                                   float* __restrict__ mstat) {
    int blk = blockIdx.x;
    int plane = blk >> 2, chunk = blk & 3;   // plane = b*2+n
    int tid = threadIdx.x;
    const float* mp = masks + (size_t)plane * 640 * 640;
    float fsum = 0.f; int cnt = 0, sy = 0, sx = 0;
    for (int p = tid; p < 1600; p += 256) {
        int y = p / WW, x = p - y * WW;
        int gy = chunk * 20 + y;
        float v = mp[(size_t)(gy * 8) * 640 + x * 8];
        m_res[(size_t)plane * HW + gy * WW + x] = v;
        fsum += v;
        if (v > 0.5f) { cnt++; sy += gy; sx += x; }
    }
    for (int off = 32; off > 0; off >>= 1) {
        fsum += __shfl_down(fsum, off, 64);
        cnt  += __shfl_down(cnt,  off, 64);
        sy   += __shfl_down(sy,   off, 64);
        sx   += __shfl_down(sx,   off, 64);
    }
    __shared__ float rf[4]; __shared__ int rc[4], ry[4], rx[4];
    int wid = tid >> 6;
    if ((tid & 63) == 0) { rf[wid] = fsum; rc[wid] = cnt; ry[wid] = sy; rx[wid] = sx; }
    __syncthreads();
    if (tid == 0) {
        float F = rf[0] + rf[1] + rf[2] + rf[3];
        int C = rc[0] + rc[1] + rc[2] + rc[3];
        int Y = ry[0] + ry[1] + ry[2] + ry[3];
        int X = rx[0] + rx[1] + rx[2] + rx[3];
        float* q = mstat + ((size_t)plane * 4 + chunk) * 4;
        q[0] = F; q[1] = (float)C; q[2] = (float)Y; q[3] = (float)X;
    }
}

// ---------------------------------------------------------------------------
// Cooperative fused kernel: pool -> grid.sync -> attn (blocks 0..63) ->
// grid.sync -> splat. 1024 blocks x 256 threads, __launch_bounds__(256,4):
// conservative co-residency (4 blocks/CU needed, >=4 guaranteed).
// ---------------------------------------------------------------------------
__global__ __launch_bounds__(256, 4) void fused_kernel(
        const float* __restrict__ x, const float* __restrict__ m_res,
        const float* __restrict__ mstat,
        const float* __restrict__ wq, const float* __restrict__ bq,
        const float* __restrict__ wk, const float* __restrict__ bk,
        const float* __restrict__ wv, const float* __restrict__ bv,
        const float* __restrict__ wo, const float* __restrict__ bo,
        const float* __restrict__ g1, const float* __restrict__ be1,
        const float* __restrict__ g2, const float* __restrict__ be2,
        const float* __restrict__ w1, const float* __restrict__ bf1,
        const float* __restrict__ w2, const float* __restrict__ bf2,
        float* __restrict__ nodes, float* __restrict__ h2g,
        float* __restrict__ out) {
    cg::grid_group grid = cg::this_grid();
    int blk = blockIdx.x;              // b*16 + cgi
    int b = blk >> 4, cgi = blk & 15;  // 8 channels per block: cgi*8 ..
    int tid = threadIdx.x;

    // ================= phase A: pool (8 channels per block) =================
    {
        const f4v* m0 = (const f4v*)(m_res + (size_t)(b * 2 + 0) * HW);
        const f4v* m1 = (const f4v*)(m_res + (size_t)(b * 2 + 1) * HW);
        const float* xbase = x + (size_t)(b * 128 + cgi * 8) * HW;
        float s[16];
        #pragma unroll
        for (int i = 0; i < 16; i++) s[i] = 0.f;
        for (int v = tid; v < HW / 4; v += 256) {
            f4v a = m0[v], bb = m1[v];
            #pragma unroll
            for (int c = 0; c < 8; c++) {
                f4v xv = ((const f4v*)(xbase + (size_t)c * HW))[v];
                s[2 * c + 0] += dot4(xv, a);
                s[2 * c + 1] += dot4(xv, bb);
            }
        }
        for (int off = 32; off > 0; off >>= 1) {
            #pragma unroll
            for (int i = 0; i < 16; i++) s[i] += __shfl_down(s[i], off, 64);
        }
        __shared__ float rpool[4][16];
        int wid = tid >> 6;
        if ((tid & 63) == 0) {
            #pragma unroll
            for (int i = 0; i < 16; i++) rpool[wid][i] = s[i];
        }
        __syncthreads();
        if (tid < 16) {
            float t = rpool[0][tid] + rpool[1][tid] + rpool[2][tid] + rpool[3][tid];
            int c4 = tid >> 1, n = tid & 1;
            nodes[(size_t)(b * 2 + n) * 128 + cgi * 8 + c4] = t;
        }
    }

    grid.sync();

    // ================= phase B: attn (blocks 0..63 only) =================
    if (blk < BB) {
        attn_core(blk, tid, nodes, mstat, wq, bq, wk, bk, wv, bv, wo, bo,
                  g1, be1, g2, be2, w1, bf1, w2, bf2, h2g, nullptr);
    }

    grid.sync();

    // ================= phase C: splat (8 channels per block, 2/wave) =========
    {
        __shared__ __align__(16) float wys[2][HH], wxs[2][WW];
        __shared__ float spos2[4];
        if (tid < 2) {
            const f4v* q = (const f4v*)(mstat + ((size_t)(b * 2 + tid) * 4) * 4);
            f4v acc = q[0] + q[1] + q[2] + q[3];
            spos2[tid * 2 + 0] = (acc.w / acc.y) * (2.f / (float)WW) - 1.f;
            spos2[tid * 2 + 1] = (acc.z / acc.y) * (2.f / (float)HH) - 1.f;
        }
        __syncthreads();
        for (int i = tid; i < 320; i += 256) {
            int seg = i / 80, off = i - seg * 80;
            float g = -1.f + (2.f / 79.f) * (float)off;
            float ctr = (seg == 0) ? spos2[1] : (seg == 1) ? spos2[3]
                      : (seg == 2) ? spos2[0] : spos2[2];
            float d = g - ctr;
            float v = __expf(-(d * d) * (1.f / SIG2F));
            if (seg == 0)      wys[0][off] = v;
            else if (seg == 1) wys[1][off] = v;
            else if (seg == 2) wxs[0][off] = v;
            else               wxs[1][off] = v;
        }
        int wv = tid >> 6, lane = tid & 63;
        int ca = cgi * 8 + wv * 2 + 0;     // two channels per wave
        int cb = cgi * 8 + wv * 2 + 1;
        float h0a = h2g[(size_t)(b * 2 + 0) * 128 + ca];
        float h1a = h2g[(size_t)(b * 2 + 1) * 128 + ca];
        float h0b = h2g[(size_t)(b * 2 + 0) * 128 + cb];
        float h1b = h2g[(size_t)(b * 2 + 1) * 128 + cb];
        __syncthreads();
        const f4v* xpa = (const f4v*)(x + (size_t)(b * 128 + ca) * HW);
        const f4v* xpb = (const f4v*)(x + (size_t)(b * 128 + cb) * HW);
        f4v* opa = (f4v*)(out + (size_t)(b * 128 + ca) * HW);
        f4v* opb = (f4v*)(out + (size_t)(b * 128 + cb) * HW);
        #pragma unroll 5
        for (int k = 0; k < 25; k++) {
            int idx = lane + 64 * k;
            int y = idx / 20, gcol = idx - y * 20;
            float wy0 = wys[0][y], wy1 = wys[1][y];
            f4v wx0 = ((const f4v*)wxs[0])[gcol];
            f4v wx1 = ((const f4v*)wxs[1])[gcol];
            f4v xa = xpa[idx];
            f4v xb = xpb[idx];
            f4v oa = xa + (h0a * wy0) * wx0 + (h1a * wy1) * wx1;
            f4v ob = xb + (h0b * wy0) * wx0 + (h1b * wy1) * wx1;
            __builtin_nontemporal_store(oa, opa + idx);
            __builtin_nontemporal_store(ob, opb + idx);
        }
    }
}

// ---------------------------------------------------------------------------
// Fallback kernels (proven round-9 trio) — used if cooperative launch fails.
// ---------------------------------------------------------------------------
__global__ __launch_bounds__(256) void pool_kernel(const float* __restrict__ x,
                                                   const float* __restrict__ m_res,
                                                   float* __restrict__ nodes) {
    int blk = blockIdx.x;              // b*32 + cg
    int b = blk >> 5, cgx = blk & 31;
    int tid = threadIdx.x;
    const f4v* m0  = (const f4v*)(m_res + (size_t)(b * 2 + 0) * HW);
    const f4v* m1  = (const f4v*)(m_res + (size_t)(b * 2 + 1) * HW);
    const f4v* xp0 = (const f4v*)(x + (size_t)(b * 128 + cgx * 4 + 0) * HW);
    const f4v* xp1 = (const f4v*)(x + (size_t)(b * 128 + cgx * 4 + 1) * HW);
    const f4v* xp2 = (const f4v*)(x + (size_t)(b * 128 + cgx * 4 + 2) * HW);
    const f4v* xp3 = (const f4v*)(x + (size_t)(b * 128 + cgx * 4 + 3) * HW);
    float s[8];
    #pragma unroll
    for (int i = 0; i < 8; i++) s[i] = 0.f;
    for (int v = tid; v < HW / 4; v += 256) {
        f4v a = m0[v], bb = m1[v];
        f4v x0 = xp0[v], x1 = xp1[v], x2 = xp2[v], x3 = xp3[v];
        s[0] += dot4(x0, a); s[1] += dot4(x0, bb);
        s[2] += dot4(x1, a); s[3] += dot4(x1, bb);
        s[4] += dot4(x2, a); s[5] += dot4(x2, bb);
        s[6] += dot4(x3, a); s[7] += dot4(x3, bb);
    }
    for (int off = 32; off > 0; off >>= 1) {
        #pragma unroll
        for (int i = 0; i < 8; i++) s[i] += __shfl_down(s[i], off, 64);
    }
    __shared__ float r[4][8];
    int wid = tid >> 6;
    if ((tid & 63) == 0) {
        #pragma unroll
        for (int i = 0; i < 8; i++) r[wid][i] = s[i];
    }
    __syncthreads();
    if (tid < 8) {
        float t = r[0][tid] + r[1][tid] + r[2][tid] + r[3][tid];
        int c4 = tid >> 1, n = tid & 1;
        nodes[(size_t)(b * 2 + n) * 128 + cgx * 4 + c4] = t;
    }
}

__global__ __launch_bounds__(256) void attn_kernel(
        const float* __restrict__ nodes, const float* __restrict__ mstat,
        const float* __restrict__ wq, const float* __restrict__ bq,
        const float* __restrict__ wk, const float* __restrict__ bk,
        const float* __restrict__ wv, const float* __restrict__ bv,
        const float* __restrict__ wo, const float* __restrict__ bo,
        const float* __restrict__ g1, const float* __restrict__ be1,
        const float* __restrict__ g2, const float* __restrict__ be2,
        const float* __restrict__ w1, const float* __restrict__ bf1,
        const float* __restrict__ w2, const float* __restrict__ bf2,
        float* __restrict__ h2out, float* __restrict__ pos_out) {
    attn_core(blockIdx.x, threadIdx.x, nodes, mstat, wq, bq, wk, bk, wv, bv,
              wo, bo, g1, be1, g2, be2, w1, bf1, w2, bf2, h2out, pos_out);
}

__global__ __launch_bounds__(320) void splat_kernel(const float* __restrict__ x,
                                                    const float* __restrict__ h2,
                                                    const float* __restrict__ pos,
                                                    float* __restrict__ out) {
    int blk = blockIdx.x;              // b*128 + c
    int b = blk >> 7, c = blk & 127;
    int tid = threadIdx.x;
    __shared__ __align__(16) float wys[2][HH], wxs[2][WW];
    if (tid < HH) {
        float g = -1.f + (2.f / 79.f) * (float)tid;
        float px0 = pos[b * 4 + 0], py0 = pos[b * 4 + 1];
        float px1 = pos[b * 4 + 2], py1 = pos[b * 4 + 3];
        float d;
        d = g - py0; wys[0][tid] = __expf(-(d * d) * (1.f / SIG2F));
        d = g - py1; wys[1][tid] = __expf(-(d * d) * (1.f / SIG2F));
        d = g - px0; wxs[0][tid] = __expf(-(d * d) * (1.f / SIG2F));
        d = g - px1; wxs[1][tid] = __expf(-(d * d) * (1.f / SIG2F));
    }
    float h0 = h2[(size_t)(b * 2 + 0) * 128 + c];
    float h1 = h2[(size_t)(b * 2 + 1) * 128 + c];
    __syncthreads();
    int gcol = tid % 20, y0 = tid / 20;
    f4v wx0 = ((const f4v*)wxs[0])[gcol];
    f4v wx1 = ((const f4v*)wxs[1])[gcol];
    const f4v* xp = (const f4v*)(x + (size_t)blk * HW);
    f4v* op = (f4v*)(out + (size_t)blk * HW);
    #pragma unroll
    for (int kk = 0; kk < 5; kk++) {
        int y = y0 + kk * 16;
        float a0 = h0 * wys[0][y], a1 = h1 * wys[1][y];
        int idx = y * 20 + gcol;
        f4v xv = xp[idx];
        f4v o = xv + a0 * wx0 + a1 * wx1;
        __builtin_nontemporal_store(o, op + idx);
    }
}

// ---------------------------------------------------------------------------
extern "C" void kernel_launch(void* const* d_in, const int* in_sizes, int n_in,
                              void* d_out, int out_size, void* d_ws, size_t ws_size,
                              hipStream_t stream) {
    const float* x     = (const float*)d_in[0];
    const float* masks = (const float*)d_in[1];
    const float* wq = (const float*)d_in[2],  *bq = (const float*)d_in[3];
    const float* wk = (const float*)d_in[4],  *bk = (const float*)d_in[5];
    const float* wv = (const float*)d_in[6],  *bv = (const float*)d_in[7];
    const float* wo = (const float*)d_in[8],  *bo = (const float*)d_in[9];
    const float* g1 = (const float*)d_in[10], *be1 = (const float*)d_in[11];
    const float* g2 = (const float*)d_in[12], *be2 = (const float*)d_in[13];
    const float* w1 = (const float*)d_in[14], *bf1 = (const float*)d_in[15];
    const float* w2 = (const float*)d_in[16], *bf2 = (const float*)d_in[17];
    float* out = (float*)d_out;

    // workspace layout (floats)
    float* ws    = (float*)d_ws;
    float* m_res = ws;                        // 64*2*6400 = 819200
    float* mstat = ws + 819200;               // 128*4*4   = 2048
    float* nodes = ws + 821248;               // 16384
    float* h2    = ws + 837632;               // 16384
    float* pos   = ws + 854016;               // 256 (fallback only)

    mask_kernel<<<BB * 2 * 4, 256, 0, stream>>>(masks, m_res, mstat);

    void* args[] = {
        (void*)&x, (void*)&m_res, (void*)&mstat,
        (void*)&wq, (void*)&bq, (void*)&wk, (void*)&bk,
        (void*)&wv, (void*)&bv, (void*)&wo, (void*)&bo,
        (void*)&g1, (void*)&be1, (void*)&g2, (void*)&be2,
        (void*)&w1, (void*)&bf1, (void*)&w2, (void*)&bf2,
        (void*)&nodes, (void*)&h2, (void*)&out
    };
    hipError_t cerr = hipLaunchCooperativeKernel((const void*)fused_kernel,
                                                 dim3(BB * 16), dim3(256),
                                                 args, 0, stream);
    if (cerr != hipSuccess) {
        (void)hipGetLastError();   // clear sticky error; use proven 3-kernel path
        pool_kernel<<<BB * 32, 256, 0, stream>>>(x, m_res, nodes);
        attn_kernel<<<BB, 256, 0, stream>>>(nodes, mstat,
                                            wq, bq, wk, bk, wv, bv, wo, bo,
                                            g1, be1, g2, be2, w1, bf1, w2, bf2,
                                            h2, pos);
        splat_kernel<<<BB * CC, 320, 0, stream>>>(x, h2, pos, out);
    }
}

// Round 16
// 139.066 us; speedup vs baseline: 2.5807x; 2.5807x over previous
//
#include <hip/hip_runtime.h>

#define BB 64
#define CC 128
#define HH 80
#define WW 80
#define HW 6400
#define SIG2F 0.18f   // 2 * 0.3^2

typedef float f4v __attribute__((ext_vector_type(4)));

__device__ __forceinline__ float dot4(f4v a, f4v b) {
    return a.x * b.x + a.y * b.y + a.z * b.z + a.w * b.w;
}

// half-block (128-thread) sum; node 0 = t<128, node 1 = t>=128 reduce
// independently; result broadcast within each half. All 256 threads call.
__device__ __forceinline__ float halfsum256(float v, int t, float* red4) {
    for (int off = 32; off > 0; off >>= 1) v += __shfl_down(v, off, 64);
    __syncthreads();
    if ((t & 63) == 0) red4[t >> 6] = v;
    __syncthreads();
    int base = (t >> 7) * 2;
    return red4[base] + red4[base + 1];
}

// ---------------------------------------------------------------------------
// Kernel A: nearest-resize masks (640->80 = stride-8 sample), store float mask,
// binary centroid -> pos, 1/(float-mask-sum + 1e-6). 128 blocks x 1024 thr.
// ---------------------------------------------------------------------------
__global__ __launch_bounds__(1024) void mask_kernel(const float* __restrict__ masks,
                                                    float* __restrict__ m_res,
                                                    float* __restrict__ pos,
                                                    float* __restrict__ invms) {
    int plane = blockIdx.x;            // b*2 + n
    int tid = threadIdx.x;
    const float* mp = masks + (size_t)plane * 640 * 640;
    float* mo = m_res + (size_t)plane * HW;
    float fsum = 0.f; int cnt = 0, sy = 0, sx = 0;
    for (int p = tid; p < HW; p += 1024) {
        int y = p / WW, x = p - y * WW;
        float v = mp[(size_t)(y * 8) * 640 + x * 8];
        mo[p] = v;
        fsum += v;
        if (v > 0.5f) { cnt++; sy += y; sx += x; }
    }
    for (int off = 32; off > 0; off >>= 1) {
        fsum += __shfl_down(fsum, off, 64);
        cnt  += __shfl_down(cnt,  off, 64);
        sy   += __shfl_down(sy,   off, 64);
        sx   += __shfl_down(sx,   off, 64);
    }
    __shared__ float rf[16];
    __shared__ int rc[16], ry[16], rx[16];
    int wid = tid >> 6;
    if ((tid & 63) == 0) { rf[wid] = fsum; rc[wid] = cnt; ry[wid] = sy; rx[wid] = sx; }
    __syncthreads();
    if (tid == 0) {
        float F = 0.f; int C = 0, Y = 0, X = 0;
        for (int i = 0; i < 16; i++) { F += rf[i]; C += rc[i]; Y += ry[i]; X += rx[i]; }
        float c = (float)C;
        pos[plane * 2 + 0] = ((float)X / c) / (float)WW * 2.f - 1.f;
        pos[plane * 2 + 1] = ((float)Y / c) / (float)HH * 2.f - 1.f;
        invms[plane] = 1.f / (F + 1e-6f);
    }
}

// ---------------------------------------------------------------------------
// Kernel B: masked average pooling, 4 channels per block.
// nodes[b,n,c] = dot(x[b,c,:,:], m[b,n,:,:]) * invms
// grid: B*32 blocks (8/CU, 32 waves/CU), 256 threads. Each m float4 pair
// feeds 4 x-streams from registers: m_res L2 traffic cut 4x vs 1ch/block.
// ---------------------------------------------------------------------------
__global__ __launch_bounds__(256) void pool_kernel(const float* __restrict__ x,
                                                   const float* __restrict__ m_res,
                                                   const float* __restrict__ invms,
                                                   float* __restrict__ nodes) {
    int blk = blockIdx.x;              // b*32 + cg
    int b = blk >> 5, cg = blk & 31;
    int tid = threadIdx.x;
    const f4v* m0  = (const f4v*)(m_res + (size_t)(b * 2 + 0) * HW);
    const f4v* m1  = (const f4v*)(m_res + (size_t)(b * 2 + 1) * HW);
    const f4v* xp0 = (const f4v*)(x + (size_t)(b * 128 + cg * 4 + 0) * HW);
    const f4v* xp1 = (const f4v*)(x + (size_t)(b * 128 + cg * 4 + 1) * HW);
    const f4v* xp2 = (const f4v*)(x + (size_t)(b * 128 + cg * 4 + 2) * HW);
    const f4v* xp3 = (const f4v*)(x + (size_t)(b * 128 + cg * 4 + 3) * HW);
    float s[8];
    #pragma unroll
    for (int i = 0; i < 8; i++) s[i] = 0.f;
    for (int v = tid; v < HW / 4; v += 256) {
        f4v a = m0[v], bb = m1[v];
        f4v x0 = xp0[v], x1 = xp1[v], x2 = xp2[v], x3 = xp3[v];
        s[0] += dot4(x0, a); s[1] += dot4(x0, bb);
        s[2] += dot4(x1, a); s[3] += dot4(x1, bb);
        s[4] += dot4(x2, a); s[5] += dot4(x2, bb);
        s[6] += dot4(x3, a); s[7] += dot4(x3, bb);
    }
    for (int off = 32; off > 0; off >>= 1) {
        #pragma unroll
        for (int i = 0; i < 8; i++) s[i] += __shfl_down(s[i], off, 64);
    }
    __shared__ float r[4][8];
    int wid = tid >> 6;
    if ((tid & 63) == 0) {
        #pragma unroll
        for (int i = 0; i < 8; i++) r[wid][i] = s[i];
    }
    __syncthreads();
    if (tid < 8) {
        float t = r[0][tid] + r[1][tid] + r[2][tid] + r[3][tid];
        int c4 = tid >> 1, n = tid & 1;
        nodes[(size_t)(b * 2 + n) * 128 + cg * 4 + c4] = t * invms[b * 2 + n];
    }
}

// ---------------------------------------------------------------------------
// Kernel C: graph attention (N=2, 4 heads x 32) + out-proj + LN + FFN + LN.
// grid: B blocks, 256 threads (t<128: node 0, t>=128: node 1), float4 weights.
// ---------------------------------------------------------------------------
__global__ __launch_bounds__(256) void attn_kernel(
        const float* __restrict__ nodes, const float* __restrict__ pos,
        const float* __restrict__ wq, const float* __restrict__ bq,
        const float* __restrict__ wk, const float* __restrict__ bk,
        const float* __restrict__ wv, const float* __restrict__ bv,
        const float* __restrict__ wo, const float* __restrict__ bo,
        const float* __restrict__ g1, const float* __restrict__ be1,
        const float* __restrict__ g2, const float* __restrict__ be2,
        const float* __restrict__ w1, const float* __restrict__ bf1,
        const float* __restrict__ w2, const float* __restrict__ bf2,
        float* __restrict__ h2out) {
    int b = blockIdx.x, t = threadIdx.x;
    int n = t >> 7, ch = t & 127;
    __shared__ __align__(16) float sn[2][128], sq[2][128], sk[2][128], sv[2][128];
    __shared__ __align__(16) float sao[2][128], sh[2][128], sf[2][256];
    __shared__ float attnw[4][2][2];
    __shared__ float red4[4];
    float nv = nodes[(size_t)(b * 2 + n) * 128 + ch];
    sn[n][ch] = nv;
    __syncthreads();
    // QKV projections: thread (n, ch), float4 weight rows
    {
        float q = bq[ch], k = bk[ch], v = bv[ch];
        const f4v* wq4 = (const f4v*)(wq + (size_t)ch * 128);
        const f4v* wk4 = (const f4v*)(wk + (size_t)ch * 128);
        const f4v* wv4 = (const f4v*)(wv + (size_t)ch * 128);
        const f4v* snn = (const f4v*)sn[n];
        #pragma unroll 4
        for (int c4 = 0; c4 < 32; c4++) {
            f4v a = snn[c4];
            q += dot4(wq4[c4], a);
            k += dot4(wk4[c4], a);
            v += dot4(wv4[c4], a);
        }
        sq[n][ch] = q; sk[n][ch] = k; sv[n][ch] = v;
    }
    __syncthreads();
    // scores + softmax (t < 128): head h = t>>5, dim d = t&31
    if (t < 128) {
        float q0 = sq[0][t], q1 = sq[1][t], k0 = sk[0][t], k1 = sk[1][t];
        float s00 = q0 * k0, s01 = q0 * k1, s10 = q1 * k0, s11 = q1 * k1;
        for (int off = 16; off > 0; off >>= 1) {
            s00 += __shfl_down(s00, off, 32);
            s01 += __shfl_down(s01, off, 32);
            s10 += __shfl_down(s10, off, 32);
            s11 += __shfl_down(s11, off, 32);
        }
        if ((t & 31) == 0) {
            int h = t >> 5;
            const float sc = 0.17677669529663687f;     // 1/sqrt(32)
            float dxp = pos[b * 4 + 0] - pos[b * 4 + 2];
            float dyp = pos[b * 4 + 1] - pos[b * 4 + 3];
            float D = sqrtf(dxp * dxp + dyp * dyp);
            float l0 = s00 * sc, l1 = s01 * sc - D;
            float mx = fmaxf(l0, l1);
            float e0 = __expf(l0 - mx), e1 = __expf(l1 - mx);
            float inv = 1.f / (e0 + e1);
            attnw[h][0][0] = e0 * inv; attnw[h][0][1] = e1 * inv;
            l0 = s10 * sc - D; l1 = s11 * sc;
            mx = fmaxf(l0, l1);
            e0 = __expf(l0 - mx); e1 = __expf(l1 - mx);
            inv = 1.f / (e0 + e1);
            attnw[h][1][0] = e0 * inv; attnw[h][1][1] = e1 * inv;
        }
    }
    __syncthreads();
    // attention-weighted V
    {
        int hh = ch >> 5;
        sao[n][ch] = attnw[hh][n][0] * sv[0][ch] + attnw[hh][n][1] * sv[1][ch];
    }
    __syncthreads();
    // out projection + residual
    float r;
    {
        float o = bo[ch];
        const f4v* wo4 = (const f4v*)(wo + (size_t)ch * 128);
        const f4v* saon = (const f4v*)sao[n];
        #pragma unroll 4
        for (int c4 = 0; c4 < 32; c4++) o += dot4(wo4[c4], saon[c4]);
        r = nv + o;
    }
    // LN1
    float mu = halfsum256(r, t, red4) * (1.f / 128.f);
    float d = r - mu;
    float var = halfsum256(d * d, t, red4) * (1.f / 128.f);
    float h = d * rsqrtf(var + 1e-5f) * g1[ch] + be1[ch];
    sh[n][ch] = h;
    __syncthreads();
    // FFN layer 1: thread t owns output j=t for BOTH nodes (weight row reuse)
    {
        float a0 = bf1[t], a1 = bf1[t];
        const f4v* w14 = (const f4v*)(w1 + (size_t)t * 128);
        const f4v* sh0 = (const f4v*)sh[0];
        const f4v* sh1 = (const f4v*)sh[1];
        #pragma unroll 4
        for (int c4 = 0; c4 < 32; c4++) {
            f4v w = w14[c4];
            a0 += dot4(w, sh0[c4]);
            a1 += dot4(w, sh1[c4]);
        }
        sf[0][t] = fmaxf(a0, 0.f);
        sf[1][t] = fmaxf(a1, 0.f);
    }
    __syncthreads();
    // FFN layer 2 + residual
    float r2;
    {
        float a = bf2[ch];
        const f4v* w24 = (const f4v*)(w2 + (size_t)ch * 256);
        const f4v* sfn = (const f4v*)sf[n];
        #pragma unroll 4
        for (int j4 = 0; j4 < 64; j4++) a += dot4(w24[j4], sfn[j4]);
        r2 = h + a;
    }
    // LN2
    float m2 = halfsum256(r2, t, red4) * (1.f / 128.f);
    float e = r2 - m2;
    float v2 = halfsum256(e * e, t, red4) * (1.f / 128.f);
    h2out[(size_t)(b * 2 + n) * 128 + ch] = e * rsqrtf(v2 + 1e-5f) * g2[ch] + be2[ch];
}

// ---------------------------------------------------------------------------
// Kernel D: separable gaussian splat + residual add.
// out[b,c,y,x] = x[b,c,y,x] + sum_n h2[b,n,c] * wy[n][y] * wx[n][x]
// 320 threads: thread tid covers idx = tid + 320k (coalesced); wx in registers.
// NT stores keep x L3-resident (validated round-10 ablation: +20 us without).
// ---------------------------------------------------------------------------
__global__ __launch_bounds__(320) void splat_kernel(const float* __restrict__ x,
                                                    const float* __restrict__ h2,
                                                    const float* __restrict__ pos,
                                                    float* __restrict__ out) {
    int blk = blockIdx.x;              // b*128 + c
    int b = blk >> 7, c = blk & 127;
    int tid = threadIdx.x;
    __shared__ __align__(16) float wys[2][HH], wxs[2][WW];
    if (tid < HH) {
        float g = -1.f + (2.f / 79.f) * (float)tid;   // linspace(-1,1,80)
        float px0 = pos[b * 4 + 0], py0 = pos[b * 4 + 1];
        float px1 = pos[b * 4 + 2], py1 = pos[b * 4 + 3];
        float d;
        d = g - py0; wys[0][tid] = __expf(-(d * d) * (1.f / SIG2F));
        d = g - py1; wys[1][tid] = __expf(-(d * d) * (1.f / SIG2F));
        d = g - px0; wxs[0][tid] = __expf(-(d * d) * (1.f / SIG2F));
        d = g - px1; wxs[1][tid] = __expf(-(d * d) * (1.f / SIG2F));
    }
    float h0 = h2[(size_t)(b * 2 + 0) * 128 + c];
    float h1 = h2[(size_t)(b * 2 + 1) * 128 + c];
    __syncthreads();
    int gcol = tid % 20, y0 = tid / 20;     // y0 in [0,16)
    f4v wx0 = ((const f4v*)wxs[0])[gcol];
    f4v wx1 = ((const f4v*)wxs[1])[gcol];
    const f4v* xp = (const f4v*)(x + (size_t)blk * HW);
    f4v* op = (f4v*)(out + (size_t)blk * HW);
    #pragma unroll
    for (int kk = 0; kk < 5; kk++) {
        int y = y0 + kk * 16;
        float a0 = h0 * wys[0][y], a1 = h1 * wys[1][y];
        int idx = y * 20 + gcol;            // == tid + kk*320, coalesced
        f4v xv = xp[idx];
        f4v o = xv + a0 * wx0 + a1 * wx1;
        __builtin_nontemporal_store(o, op + idx);
    }
}

// ---------------------------------------------------------------------------
extern "C" void kernel_launch(void* const* d_in, const int* in_sizes, int n_in,
                              void* d_out, int out_size, void* d_ws, size_t ws_size,
                              hipStream_t stream) {
    const float* x     = (const float*)d_in[0];
    const float* masks = (const float*)d_in[1];
    const float* wq = (const float*)d_in[2],  *bq = (const float*)d_in[3];
    const float* wk = (const float*)d_in[4],  *bk = (const float*)d_in[5];
    const float* wv = (const float*)d_in[6],  *bv = (const float*)d_in[7];
    const float* wo = (const float*)d_in[8],  *bo = (const float*)d_in[9];
    const float* g1 = (const float*)d_in[10], *be1 = (const float*)d_in[11];
    const float* g2 = (const float*)d_in[12], *be2 = (const float*)d_in[13];
    const float* w1 = (const float*)d_in[14], *bf1 = (const float*)d_in[15];
    const float* w2 = (const float*)d_in[16], *bf2 = (const float*)d_in[17];
    float* out = (float*)d_out;

    // workspace layout (floats)
    float* ws     = (float*)d_ws;
    float* m_res  = ws;                       // 64*2*6400 = 819200
    float* pos    = ws + 819200;              // 256
    float* invms  = ws + 819456;              // 128
    float* nodes  = ws + 819584;              // 16384
    float* h2     = ws + 835968;              // 16384   (total ~3.4 MB)

    mask_kernel<<<BB * 2, 1024, 0, stream>>>(masks, m_res, pos, invms);
    pool_kernel<<<BB * 32, 256, 0, stream>>>(x, m_res, invms, nodes);
    attn_kernel<<<BB, 256, 0, stream>>>(nodes, pos,
                                        wq, bq, wk, bk, wv, bv, wo, bo,
                                        g1, be1, g2, be2, w1, bf1, w2, bf2, h2);
    splat_kernel<<<BB * CC, 320, 0, stream>>>(x, h2, pos, out);
}